// Round 14
// baseline (824.384 us; speedup 1.0000x reference)
//
#include <hip/hip_runtime.h>
#include <hip/hip_bf16.h>

// Problem constants
#define B_    8
#define CIN   256
#define COUT  256
#define H_    128
#define W_    128
#define HP    130   // padded
#define WP    130

// Conv tile: block = 128 oc x (8 rows x 32 cols), 256 thr / 4 waves.
// Wave = 64 oc x (8 rows x 16 cols): m=4 x n=8 frags of 16x16x32.
// SINGLE A-buffer (49.2 KB total LDS -> 3 blocks/CU): phase p stages
// tile(p+1) into buf, computes rows 0-5 from aF regs (covers stage),
// mid-phase VMCNT(0)+BAR (all waves' stage landed), rows 6-9 + in-place
// aF reload <- buf, end LGKM0+BAR (WAR for next stage). 3 independent
// blocks/CU fill each other's barrier/latency stalls.
#define OCT   128
#define TROWS 8
#define TCOLS 32
#define XROWS 10    // TROWS + 2 halo
#define XCOLS 34    // TCOLS + 2 halo
#define XCH   1360  // 10*34*4 real 16B chunks
#define XCHP  1536  // padded to 6/thread
#define CCS   ((size_t)COUT * CIN)       // element stride per tap j

using bfrag = __attribute__((ext_vector_type(8))) short;   // 8 bf16 (4 VGPRs)
using f32x4 = __attribute__((ext_vector_type(4))) float;   // 4 fp32 acc

#define ASM_VMCNT(n) asm volatile("s_waitcnt vmcnt(" #n ")" ::: "memory")
#define ASM_LGKM0()  asm volatile("s_waitcnt lgkmcnt(0)" ::: "memory")
#define BAR()  do { __builtin_amdgcn_s_barrier(); __builtin_amdgcn_sched_barrier(0); } while (0)

__device__ __forceinline__ float leaky(float v) {
    return v >= 0.f ? v : 0.2f * v;
}

__device__ __forceinline__ unsigned short to_bf16(float v) {
    __hip_bfloat16 h = __float2bfloat16(v);
    return *(unsigned short*)&h;
}

// ---------------------------------------------------------------------------
// S[i][kw] = sum_{o,kh} weight[o,i,kh,kw]^2          (grid = CIN, 256 thr)
__global__ void compute_S_kernel(const float* __restrict__ weight, float* __restrict__ S) {
    const int i = blockIdx.x;
    const int t = threadIdx.x;     // = o
    const float* wp = weight + ((size_t)t * CIN + i) * 9;
    float s0 = 0.f, s1 = 0.f, s2 = 0.f;
#pragma unroll
    for (int kh = 0; kh < 3; ++kh) {
        float a = wp[kh * 3 + 0], b = wp[kh * 3 + 1], c = wp[kh * 3 + 2];
        s0 = fmaf(a, a, s0); s1 = fmaf(b, b, s1); s2 = fmaf(c, c, s2);
    }
    __shared__ float red[3][256];
    red[0][t] = s0; red[1][t] = s1; red[2][t] = s2;
    __syncthreads();
    for (int off = 128; off > 0; off >>= 1) {
        if (t < off) {
            red[0][t] += red[0][t + off];
            red[1][t] += red[1][t + off];
            red[2][t] += red[2][t + off];
        }
        __syncthreads();
    }
    if (t == 0) {
        S[i * 3 + 0] = red[0][0];
        S[i * 3 + 1] = red[1][0];
        S[i * 3 + 2] = red[2][0];
    }
}

// demod[b][kw] = rsqrt(sum_i style[b,i]^2 * S[i,kw] + 1e-8)   (grid = B)
__global__ void compute_demod_kernel(const float* __restrict__ style,
                                     const float* __restrict__ S,
                                     float* __restrict__ demod) {
    const int b = blockIdx.x;
    const int t = threadIdx.x;     // = i
    float sv = style[b * CIN + t];
    float sv2 = sv * sv;
    float s0 = sv2 * S[t * 3 + 0];
    float s1 = sv2 * S[t * 3 + 1];
    float s2 = sv2 * S[t * 3 + 2];
    __shared__ float red[3][256];
    red[0][t] = s0; red[1][t] = s1; red[2][t] = s2;
    __syncthreads();
    for (int off = 128; off > 0; off >>= 1) {
        if (t < off) {
            red[0][t] += red[0][t + off];
            red[1][t] += red[1][t + off];
            red[2][t] += red[2][t + off];
        }
        __syncthreads();
    }
    if (t == 0) {
        demod[b * 3 + 0] = rsqrtf(red[0][0] + 1e-8f);
        demod[b * 3 + 1] = rsqrtf(red[1][0] + 1e-8f);
        demod[b * 3 + 2] = rsqrtf(red[2][0] + 1e-8f);
    }
}

// wT[b][j][o][i] (bf16) = weight[o][i][j] * style[b][i] * demod[b][j%3]
// Vectorized: thread handles 8 consecutive i, one int4 store.
// grid = B*9*(COUT/8) blocks, 256 thr: (o_sub = t>>5, i-group = t&31)
__global__ void compute_wmodT_kernel(const float* __restrict__ weight,
                                     const float* __restrict__ style,
                                     const float* __restrict__ demod,
                                     unsigned short* __restrict__ wT) {
    const int bx = blockIdx.x;
    const int og = bx & 31;              // COUT/8 groups
    const int j  = (bx >> 5) % 9;
    const int b  = bx / (9 * 32);
    const int t  = threadIdx.x;
    const int o  = og * 8 + (t >> 5);
    const int i0 = (t & 31) * 8;
    const float dm = demod[b * 3 + (j % 3)];
    unsigned int u[4];
#pragma unroll
    for (int q = 0; q < 4; ++q) {
        int i = i0 + q * 2;
        float w0 = weight[((size_t)o * CIN + i) * 9 + j];
        float w1 = weight[((size_t)o * CIN + i + 1) * 9 + j];
        unsigned int lo = to_bf16(w0 * style[b * CIN + i] * dm);
        unsigned int hi = to_bf16(w1 * style[b * CIN + i + 1] * dm);
        u[q] = lo | (hi << 16);
    }
    int4 v = make_int4(u[0], u[1], u[2], u[3]);
    *(int4*)&wT[((size_t)(b * 9 + j) * COUT + o) * CIN + i0] = v;
}

// NCHW fp32 -> padded NHWC bf16 (interior) + border zero (y-slice H_).
// grid = dim3(32, H_+1, B_), 256 thr.
__global__ __launch_bounds__(256) void transpose_kernel(const float* __restrict__ x,
                                                        unsigned short* __restrict__ xT) {
    const int bx = blockIdx.x;
    const int h  = blockIdx.y;
    const int b  = blockIdx.z;
    const int t  = threadIdx.x;
    const int itile = (bx >> 2) * 32;

    if (h == H_) {
        // border: 516 px split 4 ways by (bx&3); 32 ch (itile) per block
        const int q = bx & 3;
        for (int idx = t; idx < 129 * 4; idx += 256) {
            int px_i = idx >> 2, q4 = idx & 3;
            int p = q * 129 + px_i;
            int row, col;
            if (p < 130)      { row = 0;       col = p; }
            else if (p < 260) { row = HP - 1;  col = p - 130; }
            else if (p < 388) { row = p - 259; col = 0; }
            else              { row = p - 387; col = WP - 1; }
            size_t off = ((size_t)b * HP * WP + (size_t)row * WP + col) * CIN
                         + itile + q4 * 8;
            *(int4*)((unsigned short*)xT + off) = (int4){0, 0, 0, 0};
        }
        return;
    }

    const int wtile = (bx & 3) * 32;
    __shared__ float lt[32][33];
    {   // coalesced read: consecutive t -> consecutive w
        const int tw = t & 31, tr = t >> 5;
#pragma unroll
        for (int rr = 0; rr < 4; ++rr) {
            int il = tr + rr * 8;
            lt[il][tw] = x[(((size_t)b * CIN + itile + il) * H_ + h) * W_ + wtile + tw];
        }
    }
    __syncthreads();
    {   // coalesced write: consecutive t -> consecutive i
        const int il = t & 31, wr = t >> 5;
#pragma unroll
        for (int rr = 0; rr < 4; ++rr) {
            int wl = wr + rr * 8;
            xT[(((size_t)b * HP + (h + 1)) * WP + (wtile + wl + 1)) * CIN + itile + il] =
                to_bf16(lt[il][wl]);
        }
    }
}

// ---------------------------------------------------------------------------
// Implicit-GEMM conv + leaky relu; single-A-buffer, 3 blocks/CU.
__global__ __launch_bounds__(256, 3) void conv_mfma_kernel(
    const unsigned short* __restrict__ xT,   // [8][130][130][256] bf16
    const unsigned short* __restrict__ wT,   // [8][9][256][256]  bf16
    float* __restrict__ out)
{
    const int tid = threadIdx.x;
    const int lin = blockIdx.x;               // 1024 blocks; lin&7 -> XCD = batch
    const int b    = lin & 7;
    const int rest = lin >> 3;                // 0..127
    const int oc0  = (rest & 1) * OCT;
    const int w0   = ((rest >> 1) & 3) * TCOLS;
    const int h0   = (rest >> 3) * TROWS;

    const int wid   = tid >> 6;               // 0..3
    const int lane  = tid & 63;
    const int wm    = wid >> 1;               // oc half (64 oc)
    const int cw    = wid & 1;                // col half (16 cols)
    const int l15   = lane & 15;
    const int khalf = lane >> 4;              // k-group 0..3

    __shared__ unsigned short lds_a[3 * OCT * 32];      // 24576 B ([kh][o][i])
    __shared__ unsigned short lds_x[XCHP * 8];          // 24576 B (incl pad)

    const unsigned short* xb = xT + ((size_t)(b * HP + h0) * WP + w0) * CIN;
    const unsigned short* wb = wT + ((size_t)(b * 9) * COUT + oc0) * CIN;

    // ---- per-thread gload source offsets (swizzled) ----
    int offA[6];
#pragma unroll
    for (int j = 0; j < 6; ++j) {
        int c    = (wid * 6 + j) * 64 + lane;          // [0,1536)
        int slot = c & 3;
        int o    = (c >> 2) & 127;
        int kh   = c >> 9;
        offA[j] = (int)((size_t)(kh * 3) * CCS) + o * CIN
                  + ((slot ^ ((o >> 1) & 3)) << 3);
    }

    f32x4 acc[4][8];
#pragma unroll
    for (int m = 0; m < 4; ++m)
#pragma unroll
        for (int n = 0; n < 8; ++n) acc[m][n] = (f32x4){0.f, 0.f, 0.f, 0.f};

    auto stage_A = [&](const unsigned short* wsrc) {
#pragma unroll
        for (int j = 0; j < 6; ++j) {
            __builtin_amdgcn_global_load_lds(
                (const __attribute__((address_space(1))) void*)(wsrc + offA[j]),
                (__attribute__((address_space(3))) void*)(lds_a + (wid * 6 + j) * 512),
                16, 0, 0);
        }
    };
    auto stage_X = [&](int i0) {
#pragma unroll
        for (int j = 0; j < 6; ++j) {
            int g  = (wid * 6 + j) * 64 + lane;        // [0,1536)
            int gg = g < XCH ? g : 0;                  // clamp dummies
            int pix = gg >> 2, slot = gg & 3;
            int row = pix / XCOLS, col = pix - row * XCOLS;
            int ofx = (row * WP + col) * CIN + ((slot ^ ((col >> 1) & 3)) << 3);
            __builtin_amdgcn_global_load_lds(
                (const __attribute__((address_space(1))) void*)(xb + ofx + i0),
                (__attribute__((address_space(3))) void*)(lds_x + (wid * 6 + j) * 512),
                16, 0, 0);
        }
    };

    // ---- fragment read bases ----
    const int aoff = (wm * 64 + l15) * 32 + ((khalf ^ ((l15 >> 1) & 3)) << 3);

    bfrag aF[3][4];   // current phase's 12 A-frags (pipelined across phases)

    auto loadA = [&]() {
#pragma unroll
        for (int kh = 0; kh < 3; ++kh)
#pragma unroll
            for (int m = 0; m < 4; ++m)
                aF[kh][m] = *(const bfrag*)(lds_a + aoff + ((size_t)kh * 128 + m * 16) * 32);
    };

    // kw-phase compute. aF regs = tile p. Rows 0-5 cover the just-issued
    // stage of tile(p+1); mid VMCNT(0)+BAR proves it landed (ALL waves);
    // rows 6-9 run + reload aF <- lds_a (tile p+1) at rows 7-9.
    auto compute = [&](int kw) {
        const int col = cw * 16 + l15 + kw;
        const unsigned short* bp = lds_x + col * 32 + ((khalf ^ ((col >> 1) & 3)) << 3);

        bfrag bs[3];
        bs[0] = *(const bfrag*)(bp);
        bs[1] = *(const bfrag*)(bp + (size_t)XCOLS * 32);

        __builtin_amdgcn_s_setprio(1);
#pragma unroll
        for (int r = 0; r < 6; ++r) {
            if (r < 8)
                bs[(r + 2) % 3] = *(const bfrag*)(bp + (size_t)(r + 2) * XCOLS * 32);
            const bfrag bv = bs[r % 3];
#pragma unroll
            for (int kh = 0; kh < 3; ++kh) {
                const int n = r - kh;
                if (n >= 0 && n < 8) {
#pragma unroll
                    for (int m = 0; m < 4; ++m)
                        acc[m][n] = __builtin_amdgcn_mfma_f32_16x16x32_bf16(
                            aF[kh][m], bv, acc[m][n], 0, 0, 0);
                }
            }
        }
        __builtin_amdgcn_s_setprio(0);
        // ---- mid-phase: tile(p+1) staged at phase start is now landed
        ASM_VMCNT(0);
        BAR();
        __builtin_amdgcn_s_setprio(1);
#pragma unroll
        for (int r = 6; r < 10; ++r) {
            if (r < 8)
                bs[(r + 2) % 3] = *(const bfrag*)(bp + (size_t)(r + 2) * XCOLS * 32);
            const bfrag bv = bs[r % 3];
#pragma unroll
            for (int kh = 0; kh < 3; ++kh) {
                const int n = r - kh;
                if (n >= 0 && n < 8) {
#pragma unroll
                    for (int m = 0; m < 4; ++m)
                        acc[m][n] = __builtin_amdgcn_mfma_f32_16x16x32_bf16(
                            aF[kh][m], bv, acc[m][n], 0, 0, 0);
                }
            }
            if (r >= 7) {                   // aF[r-7] dead: reload tile(p+1)
                const int kh = r - 7;
#pragma unroll
                for (int m = 0; m < 4; ++m)
                    aF[kh][m] = *(const bfrag*)(lds_a + aoff
                                  + ((size_t)kh * 128 + m * 16) * 32);
            }
        }
        __builtin_amdgcn_s_setprio(0);
    };

    // ---- prologue: X(0) + tile0 -> buf; drain; aF <- tile0; release buf
    stage_X(0);
    stage_A(wb);                             // tile0 = A(kw0, c=0)
    ASM_VMCNT(0);
    BAR();
    loadA();                                 // tile0 -> regs
    ASM_LGKM0();                             // my reads retired
    BAR();                                   // all waves' reads retired

    // Loop: phase p=3c+kw: stage tile(p+1); compute (split, mid-drain);
    // end LGKM0+BAR releases buf for the next stage.
#pragma unroll 1
    for (int c = 0; c < 8; ++c) {
        const size_t i0  = (size_t)c * 32;
        const size_t i0n = (size_t)((c + 1) & 7) * 32;  // c=7 -> dummy chunk 0

        // P0: stage tile(3c+1)=A(kw1,c); compute kw0
        stage_A(wb + 1 * CCS + i0);
        __builtin_amdgcn_sched_barrier(0);
        compute(0);
        ASM_LGKM0();
        BAR();
        // P1: stage tile(3c+2)=A(kw2,c); compute kw1
        stage_A(wb + 2 * CCS + i0);
        __builtin_amdgcn_sched_barrier(0);
        compute(1);
        ASM_LGKM0();
        BAR();
        // P2: stage tile(3c+3)=A(kw0,c+1) (dummy at c=7); compute kw2
        stage_A(wb + i0n);
        __builtin_amdgcn_sched_barrier(0);
        compute(2);
        ASM_LGKM0();
        BAR();
        // chunk boundary: X(c) fully read (retired above); restage + drain
        if (c < 7) {
            stage_X((int)i0n);
            ASM_VMCNT(0);
            BAR();
        }
    }
    ASM_VMCNT(0);   // safety drain

    // ---- epilogue: leaky relu + store (C/D: col=lane&15 -> pixel, row -> oc)
#pragma unroll
    for (int m = 0; m < 4; ++m) {
#pragma unroll
        for (int n = 0; n < 8; ++n) {
            int h = h0 + n;
            int w = w0 + cw * 16 + l15;
#pragma unroll
            for (int r = 0; r < 4; ++r) {
                int oc = oc0 + wm * 64 + m * 16 + khalf * 4 + r;
                out[(((size_t)b * COUT + oc) * H_ + h) * W_ + w] = leaky(acc[m][n][r]);
            }
        }
    }
}

// ---------------------------------------------------------------------------
extern "C" void kernel_launch(void* const* d_in, const int* in_sizes, int n_in,
                              void* d_out, int out_size, void* d_ws, size_t ws_size,
                              hipStream_t stream) {
    const float* x      = (const float*)d_in[0];  // (8,256,128,128)
    const float* style  = (const float*)d_in[1];  // (8,256)
    const float* weight = (const float*)d_in[2];  // (256,256,3,3)
    float* out = (float*)d_out;                   // (8,256,128,128)

    // ws layout: S f32[768] @0 | demod f32[24] @4096 | wT bf16 @8192 (9.4MB)
    //            | xTpad bf16 @9445376 (69.2MB)   -> total ~78.7 MB
    float* S     = (float*)d_ws;
    float* demod = (float*)((char*)d_ws + 4096);
    unsigned short* wT = (unsigned short*)((char*)d_ws + 8192);
    unsigned short* xT = (unsigned short*)((char*)d_ws + 9445376);

    compute_S_kernel<<<CIN, 256, 0, stream>>>(weight, S);
    compute_demod_kernel<<<B_, 256, 0, stream>>>(style, S, demod);
    compute_wmodT_kernel<<<B_ * 9 * 32, 256, 0, stream>>>(weight, style, demod, wT);
    transpose_kernel<<<dim3(32, H_ + 1, B_), 256, 0, stream>>>(x, xT);

    conv_mfma_kernel<<<dim3(1024), 256, 0, stream>>>(xT, wT, out);
}

// Round 15
// 188.432 us; speedup vs baseline: 4.3750x; 4.3750x over previous
//
#include <hip/hip_runtime.h>
#include <hip/hip_bf16.h>

// Problem constants
#define B_    8
#define CIN   256
#define COUT  256
#define H_    128
#define W_    128
#define HP    130   // padded
#define WP    130

// Conv tile: block = 128 oc x (8 rows x 32 cols), 256 thr / 4 waves.
// Wave = 64 oc x (8 rows x 16 cols): m=4 x n=8 frags of 16x16x32.
// KW-phases p=3c+kw, tile t=p lives in buf[t%2]. Phase p:
//   stage tile(p+2) -> buf[p%2]   (WAR-safe: buf[p%2]'s readers = phase
//                                  p-1's mid-sweep, retired by its LGKM0+BAR)
//   compute(p): aF regs hold tile p; rows 7-9 reload aF <- tile(p+1) from
//               buf[(p+1)%2]      (RAW-safe: staged at p-1, drained by p-1's
//                                  end vmcnt(0)+BAR -> all waves)
//   LGKM0; vmcnt(0); BAR          (vmcnt(0) ~free: stage issued ~2000cy ago)
// 4 barriers/chunk; zero exposed A-burst at phase start.  [r12 champion]
#define OCT   128
#define TROWS 8
#define TCOLS 32
#define XROWS 10    // TROWS + 2 halo
#define XCOLS 34    // TCOLS + 2 halo
#define XCH   1360  // 10*34*4 real 16B chunks
#define XCHP  1536  // padded to 6/thread
#define CCS   ((size_t)COUT * CIN)       // element stride per tap j

using bfrag = __attribute__((ext_vector_type(8))) short;   // 8 bf16 (4 VGPRs)
using f32x4 = __attribute__((ext_vector_type(4))) float;   // 4 fp32 acc

#define ASM_VMCNT(n) asm volatile("s_waitcnt vmcnt(" #n ")" ::: "memory")
#define ASM_LGKM0()  asm volatile("s_waitcnt lgkmcnt(0)" ::: "memory")
#define BAR()  do { __builtin_amdgcn_s_barrier(); __builtin_amdgcn_sched_barrier(0); } while (0)

__device__ __forceinline__ float leaky(float v) {
    return v >= 0.f ? v : 0.2f * v;
}

__device__ __forceinline__ unsigned short to_bf16(float v) {
    __hip_bfloat16 h = __float2bfloat16(v);
    return *(unsigned short*)&h;
}

// ---------------------------------------------------------------------------
// S[i][kw] = sum_{o,kh} weight[o,i,kh,kw]^2          (grid = CIN, 256 thr)
__global__ void compute_S_kernel(const float* __restrict__ weight, float* __restrict__ S) {
    const int i = blockIdx.x;
    const int t = threadIdx.x;     // = o
    const float* wp = weight + ((size_t)t * CIN + i) * 9;
    float s0 = 0.f, s1 = 0.f, s2 = 0.f;
#pragma unroll
    for (int kh = 0; kh < 3; ++kh) {
        float a = wp[kh * 3 + 0], b = wp[kh * 3 + 1], c = wp[kh * 3 + 2];
        s0 = fmaf(a, a, s0); s1 = fmaf(b, b, s1); s2 = fmaf(c, c, s2);
    }
    __shared__ float red[3][256];
    red[0][t] = s0; red[1][t] = s1; red[2][t] = s2;
    __syncthreads();
    for (int off = 128; off > 0; off >>= 1) {
        if (t < off) {
            red[0][t] += red[0][t + off];
            red[1][t] += red[1][t + off];
            red[2][t] += red[2][t + off];
        }
        __syncthreads();
    }
    if (t == 0) {
        S[i * 3 + 0] = red[0][0];
        S[i * 3 + 1] = red[1][0];
        S[i * 3 + 2] = red[2][0];
    }
}

// demod[b][kw] = rsqrt(sum_i style[b,i]^2 * S[i,kw] + 1e-8)   (grid = B)
__global__ void compute_demod_kernel(const float* __restrict__ style,
                                     const float* __restrict__ S,
                                     float* __restrict__ demod) {
    const int b = blockIdx.x;
    const int t = threadIdx.x;     // = i
    float sv = style[b * CIN + t];
    float sv2 = sv * sv;
    float s0 = sv2 * S[t * 3 + 0];
    float s1 = sv2 * S[t * 3 + 1];
    float s2 = sv2 * S[t * 3 + 2];
    __shared__ float red[3][256];
    red[0][t] = s0; red[1][t] = s1; red[2][t] = s2;
    __syncthreads();
    for (int off = 128; off > 0; off >>= 1) {
        if (t < off) {
            red[0][t] += red[0][t + off];
            red[1][t] += red[1][t + off];
            red[2][t] += red[2][t + off];
        }
        __syncthreads();
    }
    if (t == 0) {
        demod[b * 3 + 0] = rsqrtf(red[0][0] + 1e-8f);
        demod[b * 3 + 1] = rsqrtf(red[1][0] + 1e-8f);
        demod[b * 3 + 2] = rsqrtf(red[2][0] + 1e-8f);
    }
}

// wT[b][j][o][i] (bf16) = weight[o][i][j] * style[b][i] * demod[b][j%3]
// Vectorized: thread handles 8 consecutive i, one int4 store.
// grid = B*9*(COUT/8) blocks, 256 thr: (o_sub = t>>5, i-group = t&31)
__global__ void compute_wmodT_kernel(const float* __restrict__ weight,
                                     const float* __restrict__ style,
                                     const float* __restrict__ demod,
                                     unsigned short* __restrict__ wT) {
    const int bx = blockIdx.x;
    const int og = bx & 31;              // COUT/8 groups
    const int j  = (bx >> 5) % 9;
    const int b  = bx / (9 * 32);
    const int t  = threadIdx.x;
    const int o  = og * 8 + (t >> 5);
    const int i0 = (t & 31) * 8;
    const float dm = demod[b * 3 + (j % 3)];
    unsigned int u[4];
#pragma unroll
    for (int q = 0; q < 4; ++q) {
        int i = i0 + q * 2;
        float w0 = weight[((size_t)o * CIN + i) * 9 + j];
        float w1 = weight[((size_t)o * CIN + i + 1) * 9 + j];
        unsigned int lo = to_bf16(w0 * style[b * CIN + i] * dm);
        unsigned int hi = to_bf16(w1 * style[b * CIN + i + 1] * dm);
        u[q] = lo | (hi << 16);
    }
    int4 v = make_int4(u[0], u[1], u[2], u[3]);
    *(int4*)&wT[((size_t)(b * 9 + j) * COUT + o) * CIN + i0] = v;
}

// NCHW fp32 -> padded NHWC bf16 (interior) + border zero (y-slice H_).
// grid = dim3(32, H_+1, B_), 256 thr.
__global__ __launch_bounds__(256) void transpose_kernel(const float* __restrict__ x,
                                                        unsigned short* __restrict__ xT) {
    const int bx = blockIdx.x;
    const int h  = blockIdx.y;
    const int b  = blockIdx.z;
    const int t  = threadIdx.x;
    const int itile = (bx >> 2) * 32;

    if (h == H_) {
        // border: 516 px split 4 ways by (bx&3); 32 ch (itile) per block
        const int q = bx & 3;
        for (int idx = t; idx < 129 * 4; idx += 256) {
            int px_i = idx >> 2, q4 = idx & 3;
            int p = q * 129 + px_i;
            int row, col;
            if (p < 130)      { row = 0;       col = p; }
            else if (p < 260) { row = HP - 1;  col = p - 130; }
            else if (p < 388) { row = p - 259; col = 0; }
            else              { row = p - 387; col = WP - 1; }
            size_t off = ((size_t)b * HP * WP + (size_t)row * WP + col) * CIN
                         + itile + q4 * 8;
            *(int4*)((unsigned short*)xT + off) = (int4){0, 0, 0, 0};
        }
        return;
    }

    const int wtile = (bx & 3) * 32;
    __shared__ float lt[32][33];
    {   // coalesced read: consecutive t -> consecutive w
        const int tw = t & 31, tr = t >> 5;
#pragma unroll
        for (int rr = 0; rr < 4; ++rr) {
            int il = tr + rr * 8;
            lt[il][tw] = x[(((size_t)b * CIN + itile + il) * H_ + h) * W_ + wtile + tw];
        }
    }
    __syncthreads();
    {   // coalesced write: consecutive t -> consecutive i
        const int il = t & 31, wr = t >> 5;
#pragma unroll
        for (int rr = 0; rr < 4; ++rr) {
            int wl = wr + rr * 8;
            xT[(((size_t)b * HP + (h + 1)) * WP + (wtile + wl + 1)) * CIN + itile + il] =
                to_bf16(lt[il][wl]);
        }
    }
}

// ---------------------------------------------------------------------------
// Implicit-GEMM conv + leaky relu; KW-phased, end-drained 2-buffer A-pipeline.
__global__ __launch_bounds__(256, 2) void conv_mfma_kernel(
    const unsigned short* __restrict__ xT,   // [8][130][130][256] bf16
    const unsigned short* __restrict__ wT,   // [8][9][256][256]  bf16
    float* __restrict__ out)
{
    const int tid = threadIdx.x;
    const int lin = blockIdx.x;               // 1024 blocks; lin&7 -> XCD = batch
    const int b    = lin & 7;
    const int rest = lin >> 3;                // 0..127
    const int oc0  = (rest & 1) * OCT;
    const int w0   = ((rest >> 1) & 3) * TCOLS;
    const int h0   = (rest >> 3) * TROWS;

    const int wid   = tid >> 6;               // 0..3
    const int lane  = tid & 63;
    const int wm    = wid >> 1;               // oc half (64 oc)
    const int cw    = wid & 1;                // col half (16 cols)
    const int l15   = lane & 15;
    const int khalf = lane >> 4;              // k-group 0..3

    __shared__ unsigned short lds_a[2][3 * OCT * 32];   // 2 x 24576 B ([kh][o][i])
    __shared__ unsigned short lds_x[XCHP * 8];          // 24576 B (incl pad)

    const unsigned short* xb = xT + ((size_t)(b * HP + h0) * WP + w0) * CIN;
    const unsigned short* wb = wT + ((size_t)(b * 9) * COUT + oc0) * CIN;

    // ---- per-thread gload source offsets (swizzled) ----
    int offA[6];
#pragma unroll
    for (int j = 0; j < 6; ++j) {
        int c    = (wid * 6 + j) * 64 + lane;          // [0,1536)
        int slot = c & 3;
        int o    = (c >> 2) & 127;
        int kh   = c >> 9;
        offA[j] = (int)((size_t)(kh * 3) * CCS) + o * CIN
                  + ((slot ^ ((o >> 1) & 3)) << 3);
    }

    f32x4 acc[4][8];
#pragma unroll
    for (int m = 0; m < 4; ++m)
#pragma unroll
        for (int n = 0; n < 8; ++n) acc[m][n] = (f32x4){0.f, 0.f, 0.f, 0.f};

    auto stage_A = [&](unsigned short* dst, const unsigned short* wsrc) {
#pragma unroll
        for (int j = 0; j < 6; ++j) {
            __builtin_amdgcn_global_load_lds(
                (const __attribute__((address_space(1))) void*)(wsrc + offA[j]),
                (__attribute__((address_space(3))) void*)(dst + (wid * 6 + j) * 512),
                16, 0, 0);
        }
    };
    auto stage_X = [&](int i0) {
#pragma unroll
        for (int j = 0; j < 6; ++j) {
            int g  = (wid * 6 + j) * 64 + lane;        // [0,1536)
            int gg = g < XCH ? g : 0;                  // clamp dummies
            int pix = gg >> 2, slot = gg & 3;
            int row = pix / XCOLS, col = pix - row * XCOLS;
            int ofx = (row * WP + col) * CIN + ((slot ^ ((col >> 1) & 3)) << 3);
            __builtin_amdgcn_global_load_lds(
                (const __attribute__((address_space(1))) void*)(xb + ofx + i0),
                (__attribute__((address_space(3))) void*)(lds_x + (wid * 6 + j) * 512),
                16, 0, 0);
        }
    };

    // ---- fragment read bases ----
    const int aoff = (wm * 64 + l15) * 32 + ((khalf ^ ((l15 >> 1) & 3)) << 3);

    bfrag aF[3][4];   // current phase's 12 A-frags (pipelined across phases)

    auto loadA = [&](const unsigned short* ab) {
#pragma unroll
        for (int kh = 0; kh < 3; ++kh)
#pragma unroll
            for (int m = 0; m < 4; ++m)
                aF[kh][m] = *(const bfrag*)(ab + aoff + ((size_t)kh * 128 + m * 16) * 32);
    };

    // kw-phase compute; abn = buffer holding NEXT phase's A-tile (staged at
    // phase p-1, drained by p-1's END vmcnt(0)+BAR -> all waves). Rows 7-9
    // reload aF in place right after each frag set's last use.
    auto compute = [&](int kw, const unsigned short* abn) {
        const int col = cw * 16 + l15 + kw;
        const unsigned short* bp = lds_x + col * 32 + ((khalf ^ ((col >> 1) & 3)) << 3);

        bfrag bs[3];
        bs[0] = *(const bfrag*)(bp);
        bs[1] = *(const bfrag*)(bp + (size_t)XCOLS * 32);

        __builtin_amdgcn_s_setprio(1);
#pragma unroll
        for (int r = 0; r < 10; ++r) {
            if (r < 8)
                bs[(r + 2) % 3] = *(const bfrag*)(bp + (size_t)(r + 2) * XCOLS * 32);
            const bfrag bv = bs[r % 3];
#pragma unroll
            for (int kh = 0; kh < 3; ++kh) {
                const int n = r - kh;
                if (n >= 0 && n < 8) {
#pragma unroll
                    for (int m = 0; m < 4; ++m)
                        acc[m][n] = __builtin_amdgcn_mfma_f32_16x16x32_bf16(
                            aF[kh][m], bv, acc[m][n], 0, 0, 0);
                }
            }
            if (r >= 7) {                   // aF[r-7] dead: reload for next phase
                const int kh = r - 7;
#pragma unroll
                for (int m = 0; m < 4; ++m)
                    aF[kh][m] = *(const bfrag*)(abn + aoff
                                  + ((size_t)kh * 128 + m * 16) * 32);
            }
        }
        __builtin_amdgcn_s_setprio(0);
    };

    // ---- prologue: X(0) + tile0 -> buf0; drain; aF <- tile0; tile1 -> buf1; drain
    stage_X(0);
    stage_A(lds_a[0], wb);                   // tile0 = A(kw0, c=0)
    ASM_VMCNT(0);
    BAR();
    loadA(lds_a[0]);                         // tile0 -> regs
    ASM_LGKM0();                             // my reads retired
    BAR();                                   // all waves' reads retired
    stage_A(lds_a[1], wb + 1 * CCS);         // tile1 = A(kw1,0) -> buf1
    ASM_VMCNT(0);                            // tile1 landed (mine)
    BAR();                                   // all waves' tile1 landed

    // Loop: phase p=3c+kw. stage tile(p+2) -> buf[p%2]; compute; end-drain.
#pragma unroll 1
    for (int c = 0; c < 8; ++c) {
        unsigned short* be = lds_a[c & 1];        // buf[p%2] at kw0 (p=3c)
        unsigned short* bo = lds_a[(c & 1) ^ 1];
        const size_t i0  = (size_t)c * 32;
        const size_t i0n = (size_t)((c + 1) & 7) * 32;  // c=7 -> dummy chunk 0

        // P0: stage tile(3c+2)=A(kw2,c)->be; compute reads tile(3c+1) from bo
        stage_A(be, wb + 2 * CCS + i0);
        __builtin_amdgcn_sched_barrier(0);
        compute(0, bo);
        ASM_LGKM0(); ASM_VMCNT(0);
        BAR();
        // P1: stage tile(3c+3)=A(kw0,c+1)->bo; compute reads tile(3c+2) from be
        stage_A(bo, wb + i0n);
        __builtin_amdgcn_sched_barrier(0);
        compute(1, be);
        ASM_LGKM0(); ASM_VMCNT(0);
        BAR();
        // P2: stage tile(3c+4)=A(kw1,c+1)->be; compute reads tile(3c+3) from bo
        stage_A(be, wb + 1 * CCS + i0n);
        __builtin_amdgcn_sched_barrier(0);
        compute(2, bo);
        ASM_LGKM0(); ASM_VMCNT(0);
        BAR();
        // chunk boundary: X(c) fully read (retired above); restage + drain
        if (c < 7) {
            stage_X((int)i0n);
            ASM_VMCNT(0);
            BAR();
        }
    }
    ASM_VMCNT(0);   // safety drain

    // ---- epilogue: leaky relu + store (C/D: col=lane&15 -> pixel, row -> oc)
#pragma unroll
    for (int m = 0; m < 4; ++m) {
#pragma unroll
        for (int n = 0; n < 8; ++n) {
            int h = h0 + n;
            int w = w0 + cw * 16 + l15;
#pragma unroll
            for (int r = 0; r < 4; ++r) {
                int oc = oc0 + wm * 64 + m * 16 + khalf * 4 + r;
                out[(((size_t)b * COUT + oc) * H_ + h) * W_ + w] = leaky(acc[m][n][r]);
            }
        }
    }
}

// ---------------------------------------------------------------------------
extern "C" void kernel_launch(void* const* d_in, const int* in_sizes, int n_in,
                              void* d_out, int out_size, void* d_ws, size_t ws_size,
                              hipStream_t stream) {
    const float* x      = (const float*)d_in[0];  // (8,256,128,128)
    const float* style  = (const float*)d_in[1];  // (8,256)
    const float* weight = (const float*)d_in[2];  // (256,256,3,3)
    float* out = (float*)d_out;                   // (8,256,128,128)

    // ws layout: S f32[768] @0 | demod f32[24] @4096 | wT bf16 @8192 (9.4MB)
    //            | xTpad bf16 @9445376 (69.2MB)   -> total ~78.7 MB
    float* S     = (float*)d_ws;
    float* demod = (float*)((char*)d_ws + 4096);
    unsigned short* wT = (unsigned short*)((char*)d_ws + 8192);
    unsigned short* xT = (unsigned short*)((char*)d_ws + 9445376);

    compute_S_kernel<<<CIN, 256, 0, stream>>>(weight, S);
    compute_demod_kernel<<<B_, 256, 0, stream>>>(style, S, demod);
    compute_wmodT_kernel<<<B_ * 9 * 32, 256, 0, stream>>>(weight, style, demod, wT);
    transpose_kernel<<<dim3(32, H_ + 1, B_), 256, 0, stream>>>(x, xT);

    conv_mfma_kernel<<<dim3(1024), 256, 0, stream>>>(xT, wT, out);
}